// Round 14
// baseline (194.072 us; speedup 1.0000x reference)
//
#include <hip/hip_runtime.h>
#include <hip/hip_bf16.h>
#include <cmath>

using short4v = __attribute__((ext_vector_type(4))) short;
using f32x16  = __attribute__((ext_vector_type(16))) float;
using int8v   = __attribute__((ext_vector_type(8))) int;

// MX-scaled fp8 MFMA, K=64/instr, scales forced to 1.0 (E8M0=0x7F in every byte).
#define MFMASC(a,b,c) __builtin_amdgcn_mfma_scale_f32_32x32x64_f8f6f4( \
    a, b, c, 0, 0, 0, 0x7F7F7F7F, 0, 0x7F7F7F7F)

__device__ __forceinline__ unsigned short f2bf(float f) {
    union { float f; unsigned u; } v; v.f = f;
    unsigned u = v.u;
    return (unsigned short)((u + 0x7FFFu + ((u >> 16) & 1u)) >> 16);  // RNE
}
__device__ __forceinline__ float bf2f(unsigned short h) {
    union { unsigned u; float f; } v; v.u = ((unsigned)h) << 16;
    return v.f;
}
__device__ __forceinline__ float softplus(float x) {
    return fmaxf(x, 0.f) + log1pf(expf(-fabsf(x)));  // stable
}
__device__ __forceinline__ unsigned f4_to_fp8x4(float a, float b, float c, float d) {
    int v = __builtin_amdgcn_cvt_pk_fp8_f32(a, b, 0, false);
    v = __builtin_amdgcn_cvt_pk_fp8_f32(c, d, v, true);
    return (unsigned)v;
}
// In-place int8v builders: loads land directly in the operand's register octet
// (avoids mk8's element-insert chain -> up to 32 v_mov/kg of pure marshalling).
__device__ __forceinline__ int8v ld_a(const unsigned char* base, int o0, int o1) {
    int8v r;
    *((uint4*)&r)     = *(const uint4*)(base + o0);
    *((uint4*)&r + 1) = *(const uint4*)(base + o1);
    return r;
}
__device__ __forceinline__ int8v ld_w(const uint4* p) {
    int8v r;
    *((uint4*)&r)     = p[0];
    *((uint4*)&r + 1) = p[1];
    return r;
}

// ---- fp8 fragment pack, K=64 groups (32B/lane/kg), used as MFMA *A* operand.
// m = ct*32+(lane&31); k = kg*64 + (lane>>5)*32 + j  (j=0..31 across 8 dwords)
__global__ void pack_w_fp8g(const float* __restrict__ W, uint4* __restrict__ out,
                            int K_real, int M_real, int KG, int CT) {
    int tid = blockIdx.x * blockDim.x + threadIdx.x;
    if (tid >= CT * KG * 64) return;
    int lane = tid & 63;
    int t    = tid >> 6;
    int kg   = t % KG;
    int ct   = t / KG;
    int m  = ct * 32 + (lane & 31);
    int kb = kg * 64 + ((lane >> 5) << 5);
    float f[32];
#pragma unroll
    for (int j = 0; j < 32; ++j) {
        int k = kb + j;
        f[j] = (k < K_real && m < M_real) ? W[(size_t)k * M_real + m] : 0.f;
    }
    uint4 o0, o1;
    o0.x = f4_to_fp8x4(f[0],  f[1],  f[2],  f[3]);
    o0.y = f4_to_fp8x4(f[4],  f[5],  f[6],  f[7]);
    o0.z = f4_to_fp8x4(f[8],  f[9],  f[10], f[11]);
    o0.w = f4_to_fp8x4(f[12], f[13], f[14], f[15]);
    o1.x = f4_to_fp8x4(f[16], f[17], f[18], f[19]);
    o1.y = f4_to_fp8x4(f[20], f[21], f[22], f[23]);
    o1.z = f4_to_fp8x4(f[24], f[25], f[26], f[27]);
    o1.w = f4_to_fp8x4(f[28], f[29], f[30], f[31]);
    out[(size_t)tid * 2]     = o0;
    out[(size_t)tid * 2 + 1] = o1;
}

// ---- padded biases: [0,1024)=b1, [1024,1536)=b2, [1536,1792)=b3 ----
__global__ void pack_bias(const float* __restrict__ b1, const float* __restrict__ b2,
                          const float* __restrict__ b3, float* __restrict__ out) {
    int i = blockIdx.x * 256 + threadIdx.x;
    if (i < 1024)      out[i] = (i < 1000) ? b1[i] : 0.f;
    else if (i < 1536) { int j = i - 1024; out[i] = (j < 500) ? b2[j] : 0.f; }
    else if (i < 1792) { int j = i - 1536; out[i] = (j < 250) ? b3[j] : 0.f; }
}

// ---------------- fused MLP + loss partials ----------------
// R14 = R13 structure (2 blk/CU, MX-fp8 32x32x64, X staged once into h1's
// upper half-rows, 3 barriers in L1) + codegen: (1) in-place int8v operand
// loads (kill marshalling movs — VALUBusy was ~= MfmaUtil in R13);
// (2) unroll 2 on L2's barrier-free kg loop (scheduler pipelines W loads
// under MFMAs; no value crosses a barrier — R12's spill mode avoided).
//
// LDS map (66048 B; 2 blocks = 132KB <= 160KB):
//   [0,65536)     : h1 fp8 [64 rows][1024B], swz ^((row&15)<<4); X fp8 in
//                   bytes [512,1024) during L1.
//                   -> h2 fp8 [64][512B] at [0,32768) after L2
//                   -> h3 bf16 [64][512B] at [32768,65536) after L3
//   [65536,66048) : red[128]
__global__ __launch_bounds__(512, 4) void fused_mlp(
    const float* __restrict__ Xf, const float* __restrict__ Xr,
    const uint4* __restrict__ pW1, const uint4* __restrict__ pW2,
    const uint4* __restrict__ pW3, const float* __restrict__ biasp,
    const float* __restrict__ W4, const float* __restrict__ b4,
    float* __restrict__ partials)
{
    __shared__ __align__(16) unsigned char smem[66048];
    float* red = (float*)(smem + 65536);

    const int tidx = threadIdx.x;
    const int wid  = tidx >> 6;      // 0..7
    const int lane = tidx & 63;
    const int l31  = lane & 31;
    const int hi   = lane >> 5;
    const int swz  = (l31 & 15) << 4;   // row-swizzle (rows l31 / 32+l31 share &15)

    const long grow0 = (long)blockIdx.x * 64;   // 0..1023 fake, 1024..2047 real
    const float* X = (grow0 < 65536) ? (Xf + (size_t)grow0 * 512)
                                     : (Xr + (size_t)(grow0 - 65536) * 512);

    // ---- stage X once: fp32 HBM -> fp8 at bytes [512,1024) of each h1 row ----
#pragma unroll 1
    for (int gb = 0; gb < 4; ++gb) {
        float4 xr[4];
#pragma unroll
        for (int it = 0; it < 4; ++it) {
            int idx = (gb * 4 + it) * 512 + tidx;   // dword index 0..8191
            int r = idx >> 7; int k0 = (idx & 127) * 4;
            xr[it] = *(const float4*)(X + (size_t)r * 512 + k0);
        }
#pragma unroll
        for (int it = 0; it < 4; ++it) {
            int idx = (gb * 4 + it) * 512 + tidx;
            int r = idx >> 7; int k0 = (idx & 127) * 4;
            int pos = 512 + ((k0 & 0x1F0) ^ ((r & 15) << 4)) + (k0 & 12);
            *(unsigned*)(smem + r * 1024 + pos) =
                f4_to_fp8x4(xr[it].x, xr[it].y, xr[it].z, xr[it].w);
        }
    }
    __syncthreads();

    // ======== L1: h1^T = W1^T(A) x X(B); 2 ct-half passes, 8 straight kg each ========
#pragma unroll 1
    for (int p = 0; p < 2; ++p) {
        const uint4* wpA = pW1 + ((size_t)((p * 16 + wid * 2 + 0) * 8) * 64 + lane) * 2;
        const uint4* wpB = pW1 + ((size_t)((p * 16 + wid * 2 + 1) * 8) * 64 + lane) * 2;
        f32x16 acc[2][2];
#pragma unroll
        for (int c = 0; c < 2; ++c)
#pragma unroll
            for (int rt = 0; rt < 2; ++rt)
#pragma unroll
                for (int g = 0; g < 16; ++g) acc[c][rt][g] = 0.f;

#pragma unroll 1
        for (int kg = 0; kg < 8; ++kg) {
            int k0 = kg * 64 + hi * 32;           // 0..511
            const unsigned char* r0 = smem + l31 * 1024 + 512;
            const unsigned char* r1 = smem + (32 + l31) * 1024 + 512;
            int8v a0 = ld_a(r0, k0 ^ swz, (k0 + 16) ^ swz);
            int8v a1 = ld_a(r1, k0 ^ swz, (k0 + 16) ^ swz);
            int8v w0 = ld_w(wpA + (size_t)kg * 128);
            int8v w1 = ld_w(wpB + (size_t)kg * 128);
            acc[0][0] = MFMASC(w0, a0, acc[0][0]);
            acc[0][1] = MFMASC(w0, a1, acc[0][1]);
            acc[1][0] = MFMASC(w1, a0, acc[1][0]);
            acc[1][1] = MFMASC(w1, a1, acc[1][1]);
        }
        if (p == 1) __syncthreads();   // all waves done reading X before overwrite
        // epilogue -> h1 cols [p*512, p*512+512) = bytes [p*512, p*512+512)
#pragma unroll
        for (int c = 0; c < 2; ++c) {
            int mt = (p * 16 + wid * 2 + c) * 32;
#pragma unroll
            for (int rt = 0; rt < 2; ++rt) {
                int row = rt * 32 + l31;
#pragma unroll
                for (int q = 0; q < 4; ++q) {
                    int mg = mt + q * 8 + hi * 4;          // global h1 col, %4==0
                    float4 bb = *(const float4*)(biasp + mg);
                    float v0 = fmaxf(acc[c][rt][q * 4 + 0] + bb.x, 0.f);
                    float v1 = fmaxf(acc[c][rt][q * 4 + 1] + bb.y, 0.f);
                    float v2 = fmaxf(acc[c][rt][q * 4 + 2] + bb.z, 0.f);
                    float v3 = fmaxf(acc[c][rt][q * 4 + 3] + bb.w, 0.f);
                    *(unsigned*)(smem + row * 1024 + (mg ^ swz)) =
                        f4_to_fp8x4(v0, v1, v2, v3);
                }
            }
        }
    }
    __syncthreads();

    // ======== L2: h2^T = W2^T(A) x h1(B), K=1024 (16 kg), CT=2, RT=2 ========
    {
        const uint4* wpA = pW2 + ((size_t)((wid * 2 + 0) * 16) * 64 + lane) * 2;
        const uint4* wpB = pW2 + ((size_t)((wid * 2 + 1) * 16) * 64 + lane) * 2;
        f32x16 acc[2][2];
#pragma unroll
        for (int c = 0; c < 2; ++c)
#pragma unroll
            for (int rt = 0; rt < 2; ++rt)
#pragma unroll
                for (int g = 0; g < 16; ++g) acc[c][rt][g] = 0.f;
#pragma unroll 2
        for (int kg = 0; kg < 16; ++kg) {
            int k0 = kg * 64 + hi * 32;           // 0..1023
            const unsigned char* r0 = smem + l31 * 1024;
            const unsigned char* r1 = smem + (32 + l31) * 1024;
            int8v a0 = ld_a(r0, k0 ^ swz, (k0 + 16) ^ swz);
            int8v a1 = ld_a(r1, k0 ^ swz, (k0 + 16) ^ swz);
            int8v w0 = ld_w(wpA + (size_t)kg * 128);
            int8v w1 = ld_w(wpB + (size_t)kg * 128);
            acc[0][0] = MFMASC(w0, a0, acc[0][0]);
            acc[0][1] = MFMASC(w0, a1, acc[0][1]);
            acc[1][0] = MFMASC(w1, a0, acc[1][0]);
            acc[1][1] = MFMASC(w1, a1, acc[1][1]);
        }
        __syncthreads();   // ALL h1 reads done before h2 overwrites the region
        // epilogue -> h2 fp8 [64]x512B at [0,32768)
#pragma unroll
        for (int c = 0; c < 2; ++c) {
            int mt = (wid * 2 + c) * 32;
#pragma unroll
            for (int rt = 0; rt < 2; ++rt) {
                int row = rt * 32 + l31;
#pragma unroll
                for (int q = 0; q < 4; ++q) {
                    int mg = mt + q * 8 + hi * 4;          // 0..511
                    float4 bb = *(const float4*)(biasp + 1024 + mg);
                    float v0 = fmaxf(acc[c][rt][q * 4 + 0] + bb.x, 0.f);
                    float v1 = fmaxf(acc[c][rt][q * 4 + 1] + bb.y, 0.f);
                    float v2 = fmaxf(acc[c][rt][q * 4 + 2] + bb.z, 0.f);
                    float v3 = fmaxf(acc[c][rt][q * 4 + 3] + bb.w, 0.f);
                    *(unsigned*)(smem + row * 512 + (mg ^ swz)) =
                        f4_to_fp8x4(v0, v1, v2, v3);
                }
            }
        }
    }
    __syncthreads();

    // ======== L3: h3^T = W3^T(A) x h2(B), K=512 (8 kg), 8 waves CT=1, RT=2 ========
    {
        const uint4* wp = pW3 + ((size_t)(wid * 8) * 64 + lane) * 2;
        f32x16 acc3[2];
#pragma unroll
        for (int rt = 0; rt < 2; ++rt)
#pragma unroll
            for (int g = 0; g < 16; ++g) acc3[rt][g] = 0.f;
#pragma unroll 1
        for (int kg = 0; kg < 8; ++kg) {
            int k0 = kg * 64 + hi * 32;
            const unsigned char* r0 = smem + l31 * 512;
            const unsigned char* r1 = smem + (32 + l31) * 512;
            int8v a0 = ld_a(r0, k0 ^ swz, (k0 + 16) ^ swz);
            int8v a1 = ld_a(r1, k0 ^ swz, (k0 + 16) ^ swz);
            int8v w = ld_w(wp + (size_t)kg * 128);
            acc3[0] = MFMASC(w, a0, acc3[0]);
            acc3[1] = MFMASC(w, a1, acc3[1]);
        }
        // epilogue -> h3 bf16 [64]x512B at [32768,65536) (disjoint from h2 reads)
        int mt = wid * 32;
#pragma unroll
        for (int rt = 0; rt < 2; ++rt) {
            int row = rt * 32 + l31;
#pragma unroll
            for (int q = 0; q < 4; ++q) {
                int mg = mt + q * 8 + hi * 4;              // 0..255
                float4 bb = *(const float4*)(biasp + 1536 + mg);
                short4v s;
                s[0] = (short)f2bf(fmaxf(acc3[rt][q * 4 + 0] + bb.x, 0.f));
                s[1] = (short)f2bf(fmaxf(acc3[rt][q * 4 + 1] + bb.y, 0.f));
                s[2] = (short)f2bf(fmaxf(acc3[rt][q * 4 + 2] + bb.z, 0.f));
                s[3] = (short)f2bf(fmaxf(acc3[rt][q * 4 + 3] + bb.w, 0.f));
                *(short4v*)(smem + 32768 + row * 512 + ((mg * 2) ^ swz)) = s;
            }
        }
    }
    __syncthreads();

    // ======== L4 + loss: z = h3 . W4 + b4, 8 threads/row ========
    {
        int g  = tidx >> 3;      // row 0..63
        int t8 = tidx & 7;
        int gs = (g & 15) << 4;
        float sum = 0.f;
#pragma unroll
        for (int o = 0; o < 4; ++o) {
            int colb = t8 * 32 + o * 8;
            short4v v0 = *(const short4v*)(smem + 32768 + g * 512 + ((colb * 2) ^ gs));
            short4v v1 = *(const short4v*)(smem + 32768 + g * 512 + ((colb * 2 + 8) ^ gs));
#pragma unroll
            for (int j = 0; j < 4; ++j) {
                int c0 = colb + j, c1 = colb + 4 + j;
                if (c0 < 250) sum += bf2f((unsigned short)v0[j]) * W4[c0];
                if (c1 < 250) sum += bf2f((unsigned short)v1[j]) * W4[c1];
            }
        }
        sum += __shfl_down(sum, 4, 8);
        sum += __shfl_down(sum, 2, 8);
        sum += __shfl_down(sum, 1, 8);
        if (t8 == 0) {
            float z = sum + b4[0];
            bool fake = (grow0 < 65536);
            float spn = softplus(-z);
            red[g]      = fake ? spn : 0.f;               // loss_F part
            red[64 + g] = fake ? softplus(z) : spn;       // loss_D part
        }
    }
    __syncthreads();
    if (tidx == 0) {
        float pF = 0.f, pD = 0.f;
        for (int i = 0; i < 64; ++i) { pF += red[i]; pD += red[64 + i]; }
        partials[(size_t)blockIdx.x * 2]     = pF;
        partials[(size_t)blockIdx.x * 2 + 1] = pD;
    }
}

// ---------------- final reduction ----------------
__global__ void reduce_partials(const float* __restrict__ partials, int nblocks,
                                float* __restrict__ out) {
    __shared__ float sF[256], sD[256];
    float f = 0.f, d = 0.f;
    for (int i = threadIdx.x; i < nblocks; i += 256) {
        f += partials[2 * i];
        d += partials[2 * i + 1];
    }
    sF[threadIdx.x] = f; sD[threadIdx.x] = d;
    __syncthreads();
    for (int s = 128; s > 0; s >>= 1) {
        if (threadIdx.x < s) {
            sF[threadIdx.x] += sF[threadIdx.x + s];
            sD[threadIdx.x] += sD[threadIdx.x + s];
        }
        __syncthreads();
    }
    if (threadIdx.x == 0) { out[0] = sF[0]; out[1] = sD[0]; }
}

extern "C" void kernel_launch(void* const* d_in, const int* in_sizes, int n_in,
                              void* d_out, int out_size, void* d_ws, size_t ws_size,
                              hipStream_t stream) {
    const float* Xf = (const float*)d_in[0];   // repr_xy_hat [65536,512]
    const float* Xr = (const float*)d_in[1];   // repr_xy     [65536,512]
    const float* W1 = (const float*)d_in[2];   // [512,1000]
    const float* b1 = (const float*)d_in[3];
    const float* W2 = (const float*)d_in[4];   // [1000,500]
    const float* b2 = (const float*)d_in[5];
    const float* W3 = (const float*)d_in[6];   // [500,250]
    const float* b3 = (const float*)d_in[7];
    const float* W4 = (const float*)d_in[8];   // [250,1]
    const float* b4 = (const float*)d_in[9];

    // ws layout:
    uint4* pW1 = (uint4*)d_ws;                    // CT32 x KG8  x 64 x 32B = 512 KB
    uint4* pW2 = pW1 + 32768;                     // CT16 x KG16 x 64 x 32B = 512 KB
    uint4* pW3 = pW2 + 32768;                     // CT8  x KG8  x 64 x 32B = 128 KB
    float* biasp = (float*)(pW3 + 8192);          // 1792 floats (pad to 2048)
    float* partials = biasp + 2048;               // 2048*2 floats

    pack_w_fp8g<<<(32 * 8 * 64) / 256, 256, 0, stream>>>(W1, pW1, 512, 1000, 8, 32);
    pack_w_fp8g<<<(16 * 16 * 64) / 256, 256, 0, stream>>>(W2, pW2, 1000, 500, 16, 16);
    pack_w_fp8g<<<(8 * 8 * 64) / 256, 256, 0, stream>>>(W3, pW3, 500, 250, 8, 8);
    pack_bias<<<7, 256, 0, stream>>>(b1, b2, b3, biasp);

    fused_mlp<<<2048, 512, 0, stream>>>(Xf, Xr, pW1, pW2, pW3,
                                        biasp, W4, b4, partials);

    reduce_partials<<<1, 256, 0, stream>>>(partials, 2048, (float*)d_out);
}

// Round 15
// 186.758 us; speedup vs baseline: 1.0392x; 1.0392x over previous
//
#include <hip/hip_runtime.h>
#include <hip/hip_bf16.h>
#include <cmath>

using short4v = __attribute__((ext_vector_type(4))) short;
using f32x16  = __attribute__((ext_vector_type(16))) float;
using int8v   = __attribute__((ext_vector_type(8))) int;

// MX-scaled fp8 MFMA, K=64/instr, scales forced to 1.0 (E8M0=0x7F in every byte).
#define MFMASC(a,b,c) __builtin_amdgcn_mfma_scale_f32_32x32x64_f8f6f4( \
    a, b, c, 0, 0, 0, 0x7F7F7F7F, 0, 0x7F7F7F7F)

__device__ __forceinline__ unsigned short f2bf(float f) {
    union { float f; unsigned u; } v; v.f = f;
    unsigned u = v.u;
    return (unsigned short)((u + 0x7FFFu + ((u >> 16) & 1u)) >> 16);  // RNE
}
__device__ __forceinline__ float bf2f(unsigned short h) {
    union { unsigned u; float f; } v; v.u = ((unsigned)h) << 16;
    return v.f;
}
__device__ __forceinline__ float softplus(float x) {
    return fmaxf(x, 0.f) + log1pf(expf(-fabsf(x)));  // stable
}
__device__ __forceinline__ unsigned f4_to_fp8x4(float a, float b, float c, float d) {
    int v = __builtin_amdgcn_cvt_pk_fp8_f32(a, b, 0, false);
    v = __builtin_amdgcn_cvt_pk_fp8_f32(c, d, v, true);
    return (unsigned)v;
}
// In-place int8v builders (loads land directly in the operand register octet).
__device__ __forceinline__ int8v ld_a(const unsigned char* base, int o0, int o1) {
    int8v r;
    *((uint4*)&r)     = *(const uint4*)(base + o0);
    *((uint4*)&r + 1) = *(const uint4*)(base + o1);
    return r;
}
__device__ __forceinline__ int8v ld_w(const uint4* p) {
    int8v r;
    *((uint4*)&r)     = p[0];
    *((uint4*)&r + 1) = p[1];
    return r;
}

// ---- fp8 fragment pack helper, K=64 groups (32B/lane/kg), MFMA *A* operand.
// m = ct*32+(lane&31); k = kg*64 + (lane>>5)*32 + j  (j=0..31)
__device__ __forceinline__ void pack_one(const float* __restrict__ W,
                                         uint4* __restrict__ out,
                                         int K_real, int M_real, int KG, int tid) {
    int lane = tid & 63;
    int t    = tid >> 6;
    int kg   = t % KG;
    int ct   = t / KG;
    int m  = ct * 32 + (lane & 31);
    int kb = kg * 64 + ((lane >> 5) << 5);
    float f[32];
#pragma unroll
    for (int j = 0; j < 32; ++j) {
        int k = kb + j;
        f[j] = (k < K_real && m < M_real) ? W[(size_t)k * M_real + m] : 0.f;
    }
    uint4 o0, o1;
    o0.x = f4_to_fp8x4(f[0],  f[1],  f[2],  f[3]);
    o0.y = f4_to_fp8x4(f[4],  f[5],  f[6],  f[7]);
    o0.z = f4_to_fp8x4(f[8],  f[9],  f[10], f[11]);
    o0.w = f4_to_fp8x4(f[12], f[13], f[14], f[15]);
    o1.x = f4_to_fp8x4(f[16], f[17], f[18], f[19]);
    o1.y = f4_to_fp8x4(f[20], f[21], f[22], f[23]);
    o1.z = f4_to_fp8x4(f[24], f[25], f[26], f[27]);
    o1.w = f4_to_fp8x4(f[28], f[29], f[30], f[31]);
    out[(size_t)tid * 2]     = o0;
    out[(size_t)tid * 2 + 1] = o1;
}

// ---- single prep kernel: all 3 weight packs + padded biases (1 launch) ----
// jobs: [0,16384) W1 (KG8,CT32) | [16384,32768) W2 (KG16,CT16)
//       [32768,36864) W3 (KG8,CT8) | [36864,38656) biases
__global__ void prep_all(const float* __restrict__ W1, const float* __restrict__ W2,
                         const float* __restrict__ W3, const float* __restrict__ b1,
                         const float* __restrict__ b2, const float* __restrict__ b3,
                         uint4* __restrict__ pW1, uint4* __restrict__ pW2,
                         uint4* __restrict__ pW3, float* __restrict__ biasp) {
    int tid = blockIdx.x * 256 + threadIdx.x;
    if (tid < 16384) {
        pack_one(W1, pW1, 512, 1000, 8, tid);
    } else if (tid < 32768) {
        pack_one(W2, pW2, 1000, 500, 16, tid - 16384);
    } else if (tid < 36864) {
        pack_one(W3, pW3, 500, 250, 8, tid - 32768);
    } else if (tid < 38656) {
        int i = tid - 36864;
        if (i < 1024)      biasp[i] = (i < 1000) ? b1[i] : 0.f;
        else if (i < 1536) { int j = i - 1024; biasp[i] = (j < 500) ? b2[j] : 0.f; }
        else               { int j = i - 1536; biasp[i] = (j < 250) ? b3[j] : 0.f; }
    }
}

// ---------------- fused MLP + loss partials ----------------
// R15 = R13/R14 structure (2 blk/CU, MX-fp8 32x32x64, X staged once into h1's
// upper half-rows, 3 barriers in L1) + T5: s_setprio(1) around each kg
// iteration's MFMA cluster. The CU hosts 2 blocks at DIFFERENT phases —
// the role-diverse regime where setprio paid (+4-7%) on attn (m191), unlike
// lockstep single-block GEMM (m190 null). L2 kg loop back to unroll 1
// (R14's unroll-2 was neutral).
//
// LDS map (66048 B; 2 blocks = 132KB <= 160KB):
//   [0,65536)     : h1 fp8 [64 rows][1024B], swz ^((row&15)<<4); X fp8 in
//                   bytes [512,1024) during L1.
//                   -> h2 fp8 [64][512B] at [0,32768) after L2
//                   -> h3 bf16 [64][512B] at [32768,65536) after L3
//   [65536,66048) : red[128]
__global__ __launch_bounds__(512, 4) void fused_mlp(
    const float* __restrict__ Xf, const float* __restrict__ Xr,
    const uint4* __restrict__ pW1, const uint4* __restrict__ pW2,
    const uint4* __restrict__ pW3, const float* __restrict__ biasp,
    const float* __restrict__ W4, const float* __restrict__ b4,
    float* __restrict__ partials)
{
    __shared__ __align__(16) unsigned char smem[66048];
    float* red = (float*)(smem + 65536);

    const int tidx = threadIdx.x;
    const int wid  = tidx >> 6;      // 0..7
    const int lane = tidx & 63;
    const int l31  = lane & 31;
    const int hi   = lane >> 5;
    const int swz  = (l31 & 15) << 4;   // row-swizzle (rows l31 / 32+l31 share &15)

    const long grow0 = (long)blockIdx.x * 64;   // 0..1023 fake, 1024..2047 real
    const float* X = (grow0 < 65536) ? (Xf + (size_t)grow0 * 512)
                                     : (Xr + (size_t)(grow0 - 65536) * 512);

    // ---- stage X once: fp32 HBM -> fp8 at bytes [512,1024) of each h1 row ----
#pragma unroll 1
    for (int gb = 0; gb < 4; ++gb) {
        float4 xr[4];
#pragma unroll
        for (int it = 0; it < 4; ++it) {
            int idx = (gb * 4 + it) * 512 + tidx;   // dword index 0..8191
            int r = idx >> 7; int k0 = (idx & 127) * 4;
            xr[it] = *(const float4*)(X + (size_t)r * 512 + k0);
        }
#pragma unroll
        for (int it = 0; it < 4; ++it) {
            int idx = (gb * 4 + it) * 512 + tidx;
            int r = idx >> 7; int k0 = (idx & 127) * 4;
            int pos = 512 + ((k0 & 0x1F0) ^ ((r & 15) << 4)) + (k0 & 12);
            *(unsigned*)(smem + r * 1024 + pos) =
                f4_to_fp8x4(xr[it].x, xr[it].y, xr[it].z, xr[it].w);
        }
    }
    __syncthreads();

    // ======== L1: h1^T = W1^T(A) x X(B); 2 ct-half passes, 8 straight kg each ========
#pragma unroll 1
    for (int p = 0; p < 2; ++p) {
        const uint4* wpA = pW1 + ((size_t)((p * 16 + wid * 2 + 0) * 8) * 64 + lane) * 2;
        const uint4* wpB = pW1 + ((size_t)((p * 16 + wid * 2 + 1) * 8) * 64 + lane) * 2;
        f32x16 acc[2][2];
#pragma unroll
        for (int c = 0; c < 2; ++c)
#pragma unroll
            for (int rt = 0; rt < 2; ++rt)
#pragma unroll
                for (int g = 0; g < 16; ++g) acc[c][rt][g] = 0.f;

#pragma unroll 1
        for (int kg = 0; kg < 8; ++kg) {
            int k0 = kg * 64 + hi * 32;           // 0..511
            const unsigned char* r0 = smem + l31 * 1024 + 512;
            const unsigned char* r1 = smem + (32 + l31) * 1024 + 512;
            int8v a0 = ld_a(r0, k0 ^ swz, (k0 + 16) ^ swz);
            int8v a1 = ld_a(r1, k0 ^ swz, (k0 + 16) ^ swz);
            int8v w0 = ld_w(wpA + (size_t)kg * 128);
            int8v w1 = ld_w(wpB + (size_t)kg * 128);
            __builtin_amdgcn_s_setprio(1);
            acc[0][0] = MFMASC(w0, a0, acc[0][0]);
            acc[0][1] = MFMASC(w0, a1, acc[0][1]);
            acc[1][0] = MFMASC(w1, a0, acc[1][0]);
            acc[1][1] = MFMASC(w1, a1, acc[1][1]);
            __builtin_amdgcn_s_setprio(0);
        }
        if (p == 1) __syncthreads();   // all waves done reading X before overwrite
        // epilogue -> h1 cols [p*512, p*512+512) = bytes [p*512, p*512+512)
#pragma unroll
        for (int c = 0; c < 2; ++c) {
            int mt = (p * 16 + wid * 2 + c) * 32;
#pragma unroll
            for (int rt = 0; rt < 2; ++rt) {
                int row = rt * 32 + l31;
#pragma unroll
                for (int q = 0; q < 4; ++q) {
                    int mg = mt + q * 8 + hi * 4;          // global h1 col, %4==0
                    float4 bb = *(const float4*)(biasp + mg);
                    float v0 = fmaxf(acc[c][rt][q * 4 + 0] + bb.x, 0.f);
                    float v1 = fmaxf(acc[c][rt][q * 4 + 1] + bb.y, 0.f);
                    float v2 = fmaxf(acc[c][rt][q * 4 + 2] + bb.z, 0.f);
                    float v3 = fmaxf(acc[c][rt][q * 4 + 3] + bb.w, 0.f);
                    *(unsigned*)(smem + row * 1024 + (mg ^ swz)) =
                        f4_to_fp8x4(v0, v1, v2, v3);
                }
            }
        }
    }
    __syncthreads();

    // ======== L2: h2^T = W2^T(A) x h1(B), K=1024 (16 kg), CT=2, RT=2 ========
    {
        const uint4* wpA = pW2 + ((size_t)((wid * 2 + 0) * 16) * 64 + lane) * 2;
        const uint4* wpB = pW2 + ((size_t)((wid * 2 + 1) * 16) * 64 + lane) * 2;
        f32x16 acc[2][2];
#pragma unroll
        for (int c = 0; c < 2; ++c)
#pragma unroll
            for (int rt = 0; rt < 2; ++rt)
#pragma unroll
                for (int g = 0; g < 16; ++g) acc[c][rt][g] = 0.f;
#pragma unroll 1
        for (int kg = 0; kg < 16; ++kg) {
            int k0 = kg * 64 + hi * 32;           // 0..1023
            const unsigned char* r0 = smem + l31 * 1024;
            const unsigned char* r1 = smem + (32 + l31) * 1024;
            int8v a0 = ld_a(r0, k0 ^ swz, (k0 + 16) ^ swz);
            int8v a1 = ld_a(r1, k0 ^ swz, (k0 + 16) ^ swz);
            int8v w0 = ld_w(wpA + (size_t)kg * 128);
            int8v w1 = ld_w(wpB + (size_t)kg * 128);
            __builtin_amdgcn_s_setprio(1);
            acc[0][0] = MFMASC(w0, a0, acc[0][0]);
            acc[0][1] = MFMASC(w0, a1, acc[0][1]);
            acc[1][0] = MFMASC(w1, a0, acc[1][0]);
            acc[1][1] = MFMASC(w1, a1, acc[1][1]);
            __builtin_amdgcn_s_setprio(0);
        }
        __syncthreads();   // ALL h1 reads done before h2 overwrites the region
        // epilogue -> h2 fp8 [64]x512B at [0,32768)
#pragma unroll
        for (int c = 0; c < 2; ++c) {
            int mt = (wid * 2 + c) * 32;
#pragma unroll
            for (int rt = 0; rt < 2; ++rt) {
                int row = rt * 32 + l31;
#pragma unroll
                for (int q = 0; q < 4; ++q) {
                    int mg = mt + q * 8 + hi * 4;          // 0..511
                    float4 bb = *(const float4*)(biasp + 1024 + mg);
                    float v0 = fmaxf(acc[c][rt][q * 4 + 0] + bb.x, 0.f);
                    float v1 = fmaxf(acc[c][rt][q * 4 + 1] + bb.y, 0.f);
                    float v2 = fmaxf(acc[c][rt][q * 4 + 2] + bb.z, 0.f);
                    float v3 = fmaxf(acc[c][rt][q * 4 + 3] + bb.w, 0.f);
                    *(unsigned*)(smem + row * 512 + (mg ^ swz)) =
                        f4_to_fp8x4(v0, v1, v2, v3);
                }
            }
        }
    }
    __syncthreads();

    // ======== L3: h3^T = W3^T(A) x h2(B), K=512 (8 kg), 8 waves CT=1, RT=2 ========
    {
        const uint4* wp = pW3 + ((size_t)(wid * 8) * 64 + lane) * 2;
        f32x16 acc3[2];
#pragma unroll
        for (int rt = 0; rt < 2; ++rt)
#pragma unroll
            for (int g = 0; g < 16; ++g) acc3[rt][g] = 0.f;
#pragma unroll 1
        for (int kg = 0; kg < 8; ++kg) {
            int k0 = kg * 64 + hi * 32;
            const unsigned char* r0 = smem + l31 * 512;
            const unsigned char* r1 = smem + (32 + l31) * 512;
            int8v a0 = ld_a(r0, k0 ^ swz, (k0 + 16) ^ swz);
            int8v a1 = ld_a(r1, k0 ^ swz, (k0 + 16) ^ swz);
            int8v w = ld_w(wp + (size_t)kg * 128);
            __builtin_amdgcn_s_setprio(1);
            acc3[0] = MFMASC(w, a0, acc3[0]);
            acc3[1] = MFMASC(w, a1, acc3[1]);
            __builtin_amdgcn_s_setprio(0);
        }
        // epilogue -> h3 bf16 [64]x512B at [32768,65536) (disjoint from h2 reads)
        int mt = wid * 32;
#pragma unroll
        for (int rt = 0; rt < 2; ++rt) {
            int row = rt * 32 + l31;
#pragma unroll
            for (int q = 0; q < 4; ++q) {
                int mg = mt + q * 8 + hi * 4;              // 0..255
                float4 bb = *(const float4*)(biasp + 1536 + mg);
                short4v s;
                s[0] = (short)f2bf(fmaxf(acc3[rt][q * 4 + 0] + bb.x, 0.f));
                s[1] = (short)f2bf(fmaxf(acc3[rt][q * 4 + 1] + bb.y, 0.f));
                s[2] = (short)f2bf(fmaxf(acc3[rt][q * 4 + 2] + bb.z, 0.f));
                s[3] = (short)f2bf(fmaxf(acc3[rt][q * 4 + 3] + bb.w, 0.f));
                *(short4v*)(smem + 32768 + row * 512 + ((mg * 2) ^ swz)) = s;
            }
        }
    }
    __syncthreads();

    // ======== L4 + loss: z = h3 . W4 + b4, 8 threads/row ========
    {
        int g  = tidx >> 3;      // row 0..63
        int t8 = tidx & 7;
        int gs = (g & 15) << 4;
        float sum = 0.f;
#pragma unroll
        for (int o = 0; o < 4; ++o) {
            int colb = t8 * 32 + o * 8;
            short4v v0 = *(const short4v*)(smem + 32768 + g * 512 + ((colb * 2) ^ gs));
            short4v v1 = *(const short4v*)(smem + 32768 + g * 512 + ((colb * 2 + 8) ^ gs));
#pragma unroll
            for (int j = 0; j < 4; ++j) {
                int c0 = colb + j, c1 = colb + 4 + j;
                if (c0 < 250) sum += bf2f((unsigned short)v0[j]) * W4[c0];
                if (c1 < 250) sum += bf2f((unsigned short)v1[j]) * W4[c1];
            }
        }
        sum += __shfl_down(sum, 4, 8);
        sum += __shfl_down(sum, 2, 8);
        sum += __shfl_down(sum, 1, 8);
        if (t8 == 0) {
            float z = sum + b4[0];
            bool fake = (grow0 < 65536);
            float spn = softplus(-z);
            red[g]      = fake ? spn : 0.f;               // loss_F part
            red[64 + g] = fake ? softplus(z) : spn;       // loss_D part
        }
    }
    __syncthreads();
    if (tidx == 0) {
        float pF = 0.f, pD = 0.f;
        for (int i = 0; i < 64; ++i) { pF += red[i]; pD += red[64 + i]; }
        partials[(size_t)blockIdx.x * 2]     = pF;
        partials[(size_t)blockIdx.x * 2 + 1] = pD;
    }
}

// ---------------- final reduction ----------------
__global__ void reduce_partials(const float* __restrict__ partials, int nblocks,
                                float* __restrict__ out) {
    __shared__ float sF[256], sD[256];
    float f = 0.f, d = 0.f;
    for (int i = threadIdx.x; i < nblocks; i += 256) {
        f += partials[2 * i];
        d += partials[2 * i + 1];
    }
    sF[threadIdx.x] = f; sD[threadIdx.x] = d;
    __syncthreads();
    for (int s = 128; s > 0; s >>= 1) {
        if (threadIdx.x < s) {
            sF[threadIdx.x] += sF[threadIdx.x + s];
            sD[threadIdx.x] += sD[threadIdx.x + s];
        }
        __syncthreads();
    }
    if (threadIdx.x == 0) { out[0] = sF[0]; out[1] = sD[0]; }
}

extern "C" void kernel_launch(void* const* d_in, const int* in_sizes, int n_in,
                              void* d_out, int out_size, void* d_ws, size_t ws_size,
                              hipStream_t stream) {
    const float* Xf = (const float*)d_in[0];   // repr_xy_hat [65536,512]
    const float* Xr = (const float*)d_in[1];   // repr_xy     [65536,512]
    const float* W1 = (const float*)d_in[2];   // [512,1000]
    const float* b1 = (const float*)d_in[3];
    const float* W2 = (const float*)d_in[4];   // [1000,500]
    const float* b2 = (const float*)d_in[5];
    const float* W3 = (const float*)d_in[6];   // [500,250]
    const float* b3 = (const float*)d_in[7];
    const float* W4 = (const float*)d_in[8];   // [250,1]
    const float* b4 = (const float*)d_in[9];

    // ws layout:
    uint4* pW1 = (uint4*)d_ws;                    // CT32 x KG8  x 64 x 32B = 512 KB
    uint4* pW2 = pW1 + 32768;                     // CT16 x KG16 x 64 x 32B = 512 KB
    uint4* pW3 = pW2 + 32768;                     // CT8  x KG8  x 64 x 32B = 128 KB
    float* biasp = (float*)(pW3 + 8192);          // 1792 floats (pad to 2048)
    float* partials = biasp + 2048;               // 2048*2 floats

    prep_all<<<151, 256, 0, stream>>>(W1, W2, W3, b1, b2, b3,
                                      pW1, pW2, pW3, biasp);

    fused_mlp<<<2048, 512, 0, stream>>>(Xf, Xr, pW1, pW2, pW3,
                                        biasp, W4, b4, partials);

    reduce_partials<<<1, 256, 0, stream>>>(partials, 2048, (float*)d_out);
}

// Round 16
// 180.818 us; speedup vs baseline: 1.0733x; 1.0329x over previous
//
#include <hip/hip_runtime.h>
#include <hip/hip_bf16.h>
#include <cmath>

using short4v = __attribute__((ext_vector_type(4))) short;
using f32x16  = __attribute__((ext_vector_type(16))) float;
using int8v   = __attribute__((ext_vector_type(8))) int;

// MX-scaled fp8 MFMA, K=64/instr, scales forced to 1.0 (E8M0=0x7F in every byte).
#define MFMASC(a,b,c) __builtin_amdgcn_mfma_scale_f32_32x32x64_f8f6f4( \
    a, b, c, 0, 0, 0, 0x7F7F7F7F, 0, 0x7F7F7F7F)

__device__ __forceinline__ unsigned short f2bf(float f) {
    union { float f; unsigned u; } v; v.f = f;
    unsigned u = v.u;
    return (unsigned short)((u + 0x7FFFu + ((u >> 16) & 1u)) >> 16);  // RNE
}
__device__ __forceinline__ float bf2f(unsigned short h) {
    union { unsigned u; float f; } v; v.u = ((unsigned)h) << 16;
    return v.f;
}
__device__ __forceinline__ float softplus(float x) {
    return fmaxf(x, 0.f) + log1pf(expf(-fabsf(x)));  // stable
}
__device__ __forceinline__ unsigned f4_to_fp8x4(float a, float b, float c, float d) {
    int v = __builtin_amdgcn_cvt_pk_fp8_f32(a, b, 0, false);
    v = __builtin_amdgcn_cvt_pk_fp8_f32(c, d, v, true);
    return (unsigned)v;
}
// In-place int8v builders (loads land directly in the operand register octet).
__device__ __forceinline__ int8v ld_a(const unsigned char* base, int o0, int o1) {
    int8v r;
    *((uint4*)&r)     = *(const uint4*)(base + o0);
    *((uint4*)&r + 1) = *(const uint4*)(base + o1);
    return r;
}
__device__ __forceinline__ int8v ld_w(const uint4* p) {
    int8v r;
    *((uint4*)&r)     = p[0];
    *((uint4*)&r + 1) = p[1];
    return r;
}

// ---- fp8 fragment pack helper, K=64 groups (32B/lane/kg), MFMA *A* operand.
// m = ct*32+(lane&31); k = kg*64 + (lane>>5)*32 + j  (j=0..31)
__device__ __forceinline__ void pack_one(const float* __restrict__ W,
                                         uint4* __restrict__ out,
                                         int K_real, int M_real, int KG, int tid) {
    int lane = tid & 63;
    int t    = tid >> 6;
    int kg   = t % KG;
    int ct   = t / KG;
    int m  = ct * 32 + (lane & 31);
    int kb = kg * 64 + ((lane >> 5) << 5);
    float f[32];
#pragma unroll
    for (int j = 0; j < 32; ++j) {
        int k = kb + j;
        f[j] = (k < K_real && m < M_real) ? W[(size_t)k * M_real + m] : 0.f;
    }
    uint4 o0, o1;
    o0.x = f4_to_fp8x4(f[0],  f[1],  f[2],  f[3]);
    o0.y = f4_to_fp8x4(f[4],  f[5],  f[6],  f[7]);
    o0.z = f4_to_fp8x4(f[8],  f[9],  f[10], f[11]);
    o0.w = f4_to_fp8x4(f[12], f[13], f[14], f[15]);
    o1.x = f4_to_fp8x4(f[16], f[17], f[18], f[19]);
    o1.y = f4_to_fp8x4(f[20], f[21], f[22], f[23]);
    o1.z = f4_to_fp8x4(f[24], f[25], f[26], f[27]);
    o1.w = f4_to_fp8x4(f[28], f[29], f[30], f[31]);
    out[(size_t)tid * 2]     = o0;
    out[(size_t)tid * 2 + 1] = o1;
}

// ---- single prep kernel: all 3 weight packs + padded biases (1 launch) ----
__global__ void prep_all(const float* __restrict__ W1, const float* __restrict__ W2,
                         const float* __restrict__ W3, const float* __restrict__ b1,
                         const float* __restrict__ b2, const float* __restrict__ b3,
                         uint4* __restrict__ pW1, uint4* __restrict__ pW2,
                         uint4* __restrict__ pW3, float* __restrict__ biasp) {
    int tid = blockIdx.x * 256 + threadIdx.x;
    if (tid < 16384) {
        pack_one(W1, pW1, 512, 1000, 8, tid);
    } else if (tid < 32768) {
        pack_one(W2, pW2, 1000, 500, 16, tid - 16384);
    } else if (tid < 36864) {
        pack_one(W3, pW3, 500, 250, 8, tid - 32768);
    } else if (tid < 38656) {
        int i = tid - 36864;
        if (i < 1024)      biasp[i] = (i < 1000) ? b1[i] : 0.f;
        else if (i < 1536) { int j = i - 1024; biasp[i] = (j < 500) ? b2[j] : 0.f; }
        else               { int j = i - 1536; biasp[i] = (j < 250) ? b3[j] : 0.f; }
    }
}

// ---------------- fused MLP + loss partials ----------------
// R16: FAT WAVES. 256-thread blocks (4 waves), 2 blocks/CU (8 waves/CU) ->
// reg cap 2048/8 = 256/wave. Each wave takes CT=4 (acc 128 AGPR): per kg,
// the SAME 6 loads now feed 8 MFMAs (~136cy matrix work) instead of 4 —
// 2 waves/SIMD x 136cy ~= the ~300cy load round-trip, so the matrix pipe
// stays fed where R15's thin waves (4 MFMAs/wait, no prefetch room at the
// 128-reg cap) idled at 30%. LDS A-reads per MFMA halve (a0/a1 reused x4).
// Occupancy counter will read ~25% (8 fat waves) — expected, not regression.
// Live regs L1/L2: 128A + ~48V operands + ~20V addr ≈ 200 < 256.
//
// LDS map (66048 B; 2 blocks = 132KB <= 160KB) — unchanged from R13:
//   [0,65536)     : h1 fp8 [64 rows][1024B], swz ^((row&15)<<4); X fp8 in
//                   bytes [512,1024) during L1.
//                   -> h2 fp8 [64][512B] at [0,32768) after L2
//                   -> h3 bf16 [64][512B] at [32768,65536) after L3
//   [65536,66048) : red[128]
__global__ __launch_bounds__(256, 2) void fused_mlp(
    const float* __restrict__ Xf, const float* __restrict__ Xr,
    const uint4* __restrict__ pW1, const uint4* __restrict__ pW2,
    const uint4* __restrict__ pW3, const float* __restrict__ biasp,
    const float* __restrict__ W4, const float* __restrict__ b4,
    float* __restrict__ partials)
{
    __shared__ __align__(16) unsigned char smem[66048];
    float* red = (float*)(smem + 65536);

    const int tidx = threadIdx.x;
    const int wid  = tidx >> 6;      // 0..3
    const int lane = tidx & 63;
    const int l31  = lane & 31;
    const int hi   = lane >> 5;
    const int swz  = (l31 & 15) << 4;   // row-swizzle (rows l31 / 32+l31 share &15)

    const long grow0 = (long)blockIdx.x * 64;   // 0..1023 fake, 1024..2047 real
    const float* X = (grow0 < 65536) ? (Xf + (size_t)grow0 * 512)
                                     : (Xr + (size_t)(grow0 - 65536) * 512);

    // ---- stage X once: fp32 HBM -> fp8 at bytes [512,1024) of each h1 row ----
    // 8192 dwords; 32/thread in 8 batches of 4 (16V transient).
#pragma unroll 1
    for (int gb = 0; gb < 8; ++gb) {
        float4 xr[4];
#pragma unroll
        for (int it = 0; it < 4; ++it) {
            int idx = (gb * 4 + it) * 256 + tidx;   // dword index 0..8191
            int r = idx >> 7; int k0 = (idx & 127) * 4;
            xr[it] = *(const float4*)(X + (size_t)r * 512 + k0);
        }
#pragma unroll
        for (int it = 0; it < 4; ++it) {
            int idx = (gb * 4 + it) * 256 + tidx;
            int r = idx >> 7; int k0 = (idx & 127) * 4;
            int pos = 512 + ((k0 & 0x1F0) ^ ((r & 15) << 4)) + (k0 & 12);
            *(unsigned*)(smem + r * 1024 + pos) =
                f4_to_fp8x4(xr[it].x, xr[it].y, xr[it].z, xr[it].w);
        }
    }
    __syncthreads();

    // ======== L1: h1^T = W1^T(A) x X(B); 2 ct-half passes, CT=4/wave ========
#pragma unroll 1
    for (int p = 0; p < 2; ++p) {
        const uint4* wp0 = pW1 + ((size_t)((p * 16 + wid * 4 + 0) * 8) * 64 + lane) * 2;
        const uint4* wp1 = pW1 + ((size_t)((p * 16 + wid * 4 + 1) * 8) * 64 + lane) * 2;
        const uint4* wp2 = pW1 + ((size_t)((p * 16 + wid * 4 + 2) * 8) * 64 + lane) * 2;
        const uint4* wp3 = pW1 + ((size_t)((p * 16 + wid * 4 + 3) * 8) * 64 + lane) * 2;
        f32x16 acc[4][2];
#pragma unroll
        for (int c = 0; c < 4; ++c)
#pragma unroll
            for (int rt = 0; rt < 2; ++rt)
#pragma unroll
                for (int g = 0; g < 16; ++g) acc[c][rt][g] = 0.f;

#pragma unroll 1
        for (int kg = 0; kg < 8; ++kg) {
            int k0 = kg * 64 + hi * 32;           // 0..511
            const unsigned char* r0 = smem + l31 * 1024 + 512;
            const unsigned char* r1 = smem + (32 + l31) * 1024 + 512;
            int8v a0 = ld_a(r0, k0 ^ swz, (k0 + 16) ^ swz);
            int8v a1 = ld_a(r1, k0 ^ swz, (k0 + 16) ^ swz);
            int8v w0 = ld_w(wp0 + (size_t)kg * 128);
            int8v w1 = ld_w(wp1 + (size_t)kg * 128);
            int8v w2 = ld_w(wp2 + (size_t)kg * 128);
            int8v w3 = ld_w(wp3 + (size_t)kg * 128);
            __builtin_amdgcn_s_setprio(1);
            acc[0][0] = MFMASC(w0, a0, acc[0][0]);
            acc[0][1] = MFMASC(w0, a1, acc[0][1]);
            acc[1][0] = MFMASC(w1, a0, acc[1][0]);
            acc[1][1] = MFMASC(w1, a1, acc[1][1]);
            acc[2][0] = MFMASC(w2, a0, acc[2][0]);
            acc[2][1] = MFMASC(w2, a1, acc[2][1]);
            acc[3][0] = MFMASC(w3, a0, acc[3][0]);
            acc[3][1] = MFMASC(w3, a1, acc[3][1]);
            __builtin_amdgcn_s_setprio(0);
        }
        if (p == 1) __syncthreads();   // all waves done reading X before overwrite
        // epilogue -> h1 cols [p*512, p*512+512) = bytes [p*512, p*512+512)
#pragma unroll
        for (int c = 0; c < 4; ++c) {
            int mt = (p * 16 + wid * 4 + c) * 32;
#pragma unroll
            for (int rt = 0; rt < 2; ++rt) {
                int row = rt * 32 + l31;
#pragma unroll
                for (int q = 0; q < 4; ++q) {
                    int mg = mt + q * 8 + hi * 4;          // global h1 col, %4==0
                    float4 bb = *(const float4*)(biasp + mg);
                    float v0 = fmaxf(acc[c][rt][q * 4 + 0] + bb.x, 0.f);
                    float v1 = fmaxf(acc[c][rt][q * 4 + 1] + bb.y, 0.f);
                    float v2 = fmaxf(acc[c][rt][q * 4 + 2] + bb.z, 0.f);
                    float v3 = fmaxf(acc[c][rt][q * 4 + 3] + bb.w, 0.f);
                    *(unsigned*)(smem + row * 1024 + (mg ^ swz)) =
                        f4_to_fp8x4(v0, v1, v2, v3);
                }
            }
        }
    }
    __syncthreads();

    // ======== L2: h2^T = W2^T(A) x h1(B), K=1024 (16 kg), CT=4, RT=2 ========
    {
        const uint4* wp0 = pW2 + ((size_t)((wid * 4 + 0) * 16) * 64 + lane) * 2;
        const uint4* wp1 = pW2 + ((size_t)((wid * 4 + 1) * 16) * 64 + lane) * 2;
        const uint4* wp2 = pW2 + ((size_t)((wid * 4 + 2) * 16) * 64 + lane) * 2;
        const uint4* wp3 = pW2 + ((size_t)((wid * 4 + 3) * 16) * 64 + lane) * 2;
        f32x16 acc[4][2];
#pragma unroll
        for (int c = 0; c < 4; ++c)
#pragma unroll
            for (int rt = 0; rt < 2; ++rt)
#pragma unroll
                for (int g = 0; g < 16; ++g) acc[c][rt][g] = 0.f;
#pragma unroll 1
        for (int kg = 0; kg < 16; ++kg) {
            int k0 = kg * 64 + hi * 32;           // 0..1023
            const unsigned char* r0 = smem + l31 * 1024;
            const unsigned char* r1 = smem + (32 + l31) * 1024;
            int8v a0 = ld_a(r0, k0 ^ swz, (k0 + 16) ^ swz);
            int8v a1 = ld_a(r1, k0 ^ swz, (k0 + 16) ^ swz);
            int8v w0 = ld_w(wp0 + (size_t)kg * 128);
            int8v w1 = ld_w(wp1 + (size_t)kg * 128);
            int8v w2 = ld_w(wp2 + (size_t)kg * 128);
            int8v w3 = ld_w(wp3 + (size_t)kg * 128);
            __builtin_amdgcn_s_setprio(1);
            acc[0][0] = MFMASC(w0, a0, acc[0][0]);
            acc[0][1] = MFMASC(w0, a1, acc[0][1]);
            acc[1][0] = MFMASC(w1, a0, acc[1][0]);
            acc[1][1] = MFMASC(w1, a1, acc[1][1]);
            acc[2][0] = MFMASC(w2, a0, acc[2][0]);
            acc[2][1] = MFMASC(w2, a1, acc[2][1]);
            acc[3][0] = MFMASC(w3, a0, acc[3][0]);
            acc[3][1] = MFMASC(w3, a1, acc[3][1]);
            __builtin_amdgcn_s_setprio(0);
        }
        __syncthreads();   // ALL h1 reads done before h2 overwrites the region
        // epilogue -> h2 fp8 [64]x512B at [0,32768)
#pragma unroll
        for (int c = 0; c < 4; ++c) {
            int mt = (wid * 4 + c) * 32;
#pragma unroll
            for (int rt = 0; rt < 2; ++rt) {
                int row = rt * 32 + l31;
#pragma unroll
                for (int q = 0; q < 4; ++q) {
                    int mg = mt + q * 8 + hi * 4;          // 0..511
                    float4 bb = *(const float4*)(biasp + 1024 + mg);
                    float v0 = fmaxf(acc[c][rt][q * 4 + 0] + bb.x, 0.f);
                    float v1 = fmaxf(acc[c][rt][q * 4 + 1] + bb.y, 0.f);
                    float v2 = fmaxf(acc[c][rt][q * 4 + 2] + bb.z, 0.f);
                    float v3 = fmaxf(acc[c][rt][q * 4 + 3] + bb.w, 0.f);
                    *(unsigned*)(smem + row * 512 + (mg ^ swz)) =
                        f4_to_fp8x4(v0, v1, v2, v3);
                }
            }
        }
    }
    __syncthreads();

    // ======== L3: h3^T = W3^T(A) x h2(B), K=512 (8 kg), 4 waves CT=2, RT=2 ========
    {
        const uint4* wp0 = pW3 + ((size_t)((wid * 2 + 0) * 8) * 64 + lane) * 2;
        const uint4* wp1 = pW3 + ((size_t)((wid * 2 + 1) * 8) * 64 + lane) * 2;
        f32x16 acc3[2][2];
#pragma unroll
        for (int c = 0; c < 2; ++c)
#pragma unroll
            for (int rt = 0; rt < 2; ++rt)
#pragma unroll
                for (int g = 0; g < 16; ++g) acc3[c][rt][g] = 0.f;
#pragma unroll 1
        for (int kg = 0; kg < 8; ++kg) {
            int k0 = kg * 64 + hi * 32;
            const unsigned char* r0 = smem + l31 * 512;
            const unsigned char* r1 = smem + (32 + l31) * 512;
            int8v a0 = ld_a(r0, k0 ^ swz, (k0 + 16) ^ swz);
            int8v a1 = ld_a(r1, k0 ^ swz, (k0 + 16) ^ swz);
            int8v w0 = ld_w(wp0 + (size_t)kg * 128);
            int8v w1 = ld_w(wp1 + (size_t)kg * 128);
            __builtin_amdgcn_s_setprio(1);
            acc3[0][0] = MFMASC(w0, a0, acc3[0][0]);
            acc3[0][1] = MFMASC(w0, a1, acc3[0][1]);
            acc3[1][0] = MFMASC(w1, a0, acc3[1][0]);
            acc3[1][1] = MFMASC(w1, a1, acc3[1][1]);
            __builtin_amdgcn_s_setprio(0);
        }
        // epilogue -> h3 bf16 [64]x512B at [32768,65536) (disjoint from h2 reads)
#pragma unroll
        for (int c = 0; c < 2; ++c) {
            int mt = (wid * 2 + c) * 32;
#pragma unroll
            for (int rt = 0; rt < 2; ++rt) {
                int row = rt * 32 + l31;
#pragma unroll
                for (int q = 0; q < 4; ++q) {
                    int mg = mt + q * 8 + hi * 4;          // 0..255
                    float4 bb = *(const float4*)(biasp + 1536 + mg);
                    short4v s;
                    s[0] = (short)f2bf(fmaxf(acc3[c][rt][q * 4 + 0] + bb.x, 0.f));
                    s[1] = (short)f2bf(fmaxf(acc3[c][rt][q * 4 + 1] + bb.y, 0.f));
                    s[2] = (short)f2bf(fmaxf(acc3[c][rt][q * 4 + 2] + bb.z, 0.f));
                    s[3] = (short)f2bf(fmaxf(acc3[c][rt][q * 4 + 3] + bb.w, 0.f));
                    *(short4v*)(smem + 32768 + row * 512 + ((mg * 2) ^ swz)) = s;
                }
            }
        }
    }
    __syncthreads();

    // ======== L4 + loss: z = h3 . W4 + b4, 4 threads/row ========
    {
        int g  = tidx >> 2;      // row 0..63
        int t4 = tidx & 3;
        int gs = (g & 15) << 4;
        float sum = 0.f;
#pragma unroll
        for (int o = 0; o < 8; ++o) {
            int colb = t4 * 64 + o * 8;                    // 0..248
            short4v v0 = *(const short4v*)(smem + 32768 + g * 512 + ((colb * 2) ^ gs));
            short4v v1 = *(const short4v*)(smem + 32768 + g * 512 + ((colb * 2 + 8) ^ gs));
#pragma unroll
            for (int j = 0; j < 4; ++j) {
                int c0 = colb + j, c1 = colb + 4 + j;
                if (c0 < 250) sum += bf2f((unsigned short)v0[j]) * W4[c0];
                if (c1 < 250) sum += bf2f((unsigned short)v1[j]) * W4[c1];
            }
        }
        sum += __shfl_down(sum, 2, 4);
        sum += __shfl_down(sum, 1, 4);
        if (t4 == 0) {
            float z = sum + b4[0];
            bool fake = (grow0 < 65536);
            float spn = softplus(-z);
            red[g]      = fake ? spn : 0.f;               // loss_F part
            red[64 + g] = fake ? softplus(z) : spn;       // loss_D part
        }
    }
    __syncthreads();
    if (tidx == 0) {
        float pF = 0.f, pD = 0.f;
        for (int i = 0; i < 64; ++i) { pF += red[i]; pD += red[64 + i]; }
        partials[(size_t)blockIdx.x * 2]     = pF;
        partials[(size_t)blockIdx.x * 2 + 1] = pD;
    }
}

// ---------------- final reduction ----------------
__global__ void reduce_partials(const float* __restrict__ partials, int nblocks,
                                float* __restrict__ out) {
    __shared__ float sF[256], sD[256];
    float f = 0.f, d = 0.f;
    for (int i = threadIdx.x; i < nblocks; i += 256) {
        f += partials[2 * i];
        d += partials[2 * i + 1];
    }
    sF[threadIdx.x] = f; sD[threadIdx.x] = d;
    __syncthreads();
    for (int s = 128; s > 0; s >>= 1) {
        if (threadIdx.x < s) {
            sF[threadIdx.x] += sF[threadIdx.x + s];
            sD[threadIdx.x] += sD[threadIdx.x + s];
        }
        __syncthreads();
    }
    if (threadIdx.x == 0) { out[0] = sF[0]; out[1] = sD[0]; }
}

extern "C" void kernel_launch(void* const* d_in, const int* in_sizes, int n_in,
                              void* d_out, int out_size, void* d_ws, size_t ws_size,
                              hipStream_t stream) {
    const float* Xf = (const float*)d_in[0];   // repr_xy_hat [65536,512]
    const float* Xr = (const float*)d_in[1];   // repr_xy     [65536,512]
    const float* W1 = (const float*)d_in[2];   // [512,1000]
    const float* b1 = (const float*)d_in[3];
    const float* W2 = (const float*)d_in[4];   // [1000,500]
    const float* b2 = (const float*)d_in[5];
    const float* W3 = (const float*)d_in[6];   // [500,250]
    const float* b3 = (const float*)d_in[7];
    const float* W4 = (const float*)d_in[8];   // [250,1]
    const float* b4 = (const float*)d_in[9];

    // ws layout:
    uint4* pW1 = (uint4*)d_ws;                    // CT32 x KG8  x 64 x 32B = 512 KB
    uint4* pW2 = pW1 + 32768;                     // CT16 x KG16 x 64 x 32B = 512 KB
    uint4* pW3 = pW2 + 32768;                     // CT8  x KG8  x 64 x 32B = 128 KB
    float* biasp = (float*)(pW3 + 8192);          // 1792 floats (pad to 2048)
    float* partials = biasp + 2048;               // 2048*2 floats

    prep_all<<<151, 256, 0, stream>>>(W1, W2, W3, b1, b2, b3,
                                      pW1, pW2, pW3, biasp);

    fused_mlp<<<2048, 256, 0, stream>>>(Xf, Xr, pW1, pW2, pW3,
                                        biasp, W4, b4, partials);

    reduce_partials<<<1, 256, 0, stream>>>(partials, 2048, (float*)d_out);
}